// Round 14
// baseline (69.215 us; speedup 1.0000x reference)
//
#include <hip/hip_runtime.h>

#define NB 16
#define IN_CH 64
#define OUT_CH 256
#define NH 48
#define NW 48
#define NPIX (NH * NW)                 // 2304
#define ROW_STRIDE 52                  // dwords per staged halo row
#define HALO_ROWS 6                    // 4-row band + 2 halo
#define CH_STRIDE (HALO_ROWS * ROW_STRIDE)  // 312 dwords per channel
#define LDS_DW (IN_CH * CH_STRIDE)     // 19968 dwords = 79,872 B -> 2 blocks/CU
#define NITEMS (IN_CH * HALO_ROWS * 26) // 9984 float2 staging items
#define META_F4 9                      // per o: [0..1]=8 int offsets, [2..8]=7 node weights

__constant__ float c_gate[16 * 4] = {
    0.f, 0.f, 0.f, 0.f,
    0.f, 0.f, 0.f, 1.f,
    0.f, 1.f, 0.f, -1.f,
    0.f, 1.f, 0.f, 0.f,
    0.f, 0.f, 1.f, -1.f,
    0.f, 0.f, 1.f, 0.f,
    0.f, 1.f, 1.f, -2.f,
    0.f, 1.f, 1.f, -1.f,
    1.f, -1.f, -1.f, 1.f,
    1.f, -1.f, -1.f, 2.f,
    1.f, 0.f, -1.f, 0.f,
    1.f, 0.f, -1.f, 1.f,
    1.f, -1.f, 0.f, 0.f,
    1.f, -1.f, 0.f, 1.f,
    1.f, 0.f, 0.f, -1.f,
    1.f, 0.f, 0.f, 0.f
};

// meta[o][36 dw]: 0..7 = int LDS dword offsets (c*CH_STRIDE + di*ROW_STRIDE + dj),
//                8..35 = 7 nodes x 4 floats (softmax(logits) @ GATE_COEFF)
__global__ __launch_bounds__(256) void prep_kernel(
    const float* __restrict__ logits,
    const int*   __restrict__ leaf_idx,
    float*       __restrict__ meta)
{
    int t = blockIdx.x * 256 + threadIdx.x;
    if (t < OUT_CH * 8) {
        int idx = leaf_idx[t];
        int c  = idx / 9;
        int k  = idx - c * 9;
        int di = k / 3;
        int dj = k - di * 3;
        reinterpret_cast<int*>(meta)[(t >> 3) * 36 + (t & 7)] =
            c * CH_STRIDE + di * ROW_STRIDE + dj;
    } else {
        int t2 = t - OUT_CH * 8;
        if (t2 >= OUT_CH * 7) return;
        int o = t2 / 7;
        int n = t2 - o * 7;
        const float* lg = logits + (size_t)t2 * 16;

        float m = lg[0];
#pragma unroll
        for (int g = 1; g < 16; ++g) m = fmaxf(m, lg[g]);
        float e16[16];
        float s = 0.f;
#pragma unroll
        for (int g = 0; g < 16; ++g) { e16[g] = expf(lg[g] - m); s += e16[g]; }
        float inv = 1.f / s;

        float w0 = 0.f, w1 = 0.f, w2 = 0.f, w3 = 0.f;
#pragma unroll
        for (int g = 0; g < 16; ++g) {
            float p = e16[g] * inv;
            w0 += p * c_gate[g * 4 + 0];
            w1 += p * c_gate[g * 4 + 1];
            w2 += p * c_gate[g * 4 + 2];
            w3 += p * c_gate[g * 4 + 3];
        }
        float* mw = meta + o * 36 + 8 + n * 4;
        mw[0] = w0; mw[1] = w1; mw[2] = w2; mw[3] = w3;
    }
}

__device__ __forceinline__ float tree8(
    const float v0, const float v1, const float v2, const float v3,
    const float v4, const float v5, const float v6, const float v7,
    const float4& W0, const float4& W1, const float4& W2, const float4& W3,
    const float4& W4, const float4& W5, const float4& W6)
{
    float t0 = fmaf(v1, fmaf(W0.w, v0, W0.z), fmaf(W0.y, v0, W0.x));
    float t1 = fmaf(v3, fmaf(W1.w, v2, W1.z), fmaf(W1.y, v2, W1.x));
    float t2 = fmaf(v5, fmaf(W2.w, v4, W2.z), fmaf(W2.y, v4, W2.x));
    float t3 = fmaf(v7, fmaf(W3.w, v6, W3.z), fmaf(W3.y, v6, W3.x));
    float u0 = fmaf(t1, fmaf(W4.w, t0, W4.z), fmaf(W4.y, t0, W4.x));
    float u1 = fmaf(t3, fmaf(W5.w, t2, W5.z), fmaf(W5.y, t2, W5.x));
    return fmaf(u1, fmaf(W6.w, u0, W6.z), fmaf(W6.y, u0, W6.x));
}

// grid = (12 four-row bands, 4 o-quarters, 16 batches), block 512 (8 waves),
// 2 blocks/CU (LDS 80KB), __launch_bounds__(512,4) -> VGPR cap 128.
// Wave = 2 og x 32 lanes; og-group walks 4 channels. Lane pxg covers 6 px:
// {G+pxg} rows0-1 and {G+pxg+96} rows2-3 for G in {0,32,64}. The vertical
// pair is ALWAYS +2 rows, same column -> LDS delta = 2*ROW_STRIDE = 104,
// lane-uniform -> ds_read2_b32 {0,104}: 24 read2/iter covering 192 px
// (R12: 24 b32 per 96 px -> 2x fewer DS insts, zero divergent deltas).
// Stores: 6 x 32-lane-contiguous 128B groups (proven pattern, no RMW).
__global__ __launch_bounds__(512, 4) void ltc_kernel(
    const float*  __restrict__ x,     // [B][64][48][48]
    const float4* __restrict__ meta,  // [OUT_CH][9]
    float*        __restrict__ out)   // [B][OUT_CH][48][48]
{
    __shared__ float lds[LDS_DW];

    const int band = blockIdx.x;      // 0..11
    const int oq   = blockIdx.y;      // 0..3
    const int b    = blockIdx.z;      // 0..15
    const int r0   = band * 4;
    const int tid  = threadIdx.x;

    // ---- stage 6-row halo as float2: layout [c][6][52], image col g at lds col g+2 ----
    const float* xb = x + (size_t)b * IN_CH * NPIX;
    for (int it = tid; it < NITEMS; it += 512) {
        int c   = it / 156;                 // 156 = 6 rows * 26 pairs
        int rem = it - c * 156;
        int r6  = rem / 26;
        int p   = rem - r6 * 26;            // pair: lds cols 2p, 2p+1
        int gr  = r0 - 1 + r6;
        float2 v = make_float2(0.f, 0.f);
        if (p > 0 && p < 25 && (unsigned)gr < NH)
            v = *reinterpret_cast<const float2*>(xb + (c * NH + gr) * NW + (2 * p - 2));
        *reinterpret_cast<float2*>(&lds[c * CH_STRIDE + r6 * ROW_STRIDE + 2 * p]) = v;
    }
    __syncthreads();

    const int lane = tid & 63;
    const int wid  = tid >> 6;               // 0..7
    const int og   = lane >> 5;              // 0..1
    const int pxg  = lane & 31;              // 0..31
    const int o0   = oq * 64 + ((wid << 1) | og) * 4;   // first of 4 channels

    // per-lane bases for the 3 horizontal px-groups (rows 0-1 of the band):
    // B(px) = (px/48)*ROW_STRIDE + px%48 + 1; vertical partner = +104.
    int bases[3];
#pragma unroll
    for (int g = 0; g < 3; ++g) {
        int px = g * 32 + pxg;               // 0..95
        int rr = (px >= 48) ? 1 : 0;
        int cc = px - rr * 48;
        bases[g] = rr * ROW_STRIDE + cc + 1;
    }

    const float4* mptr  = meta + (size_t)o0 * META_F4;
    float*        pbase = out + ((size_t)b * OUT_CH + o0) * NPIX + r0 * NW + pxg;

#pragma unroll 1
    for (int i = 0; i < 4; ++i) {
        float4 M0 = mptr[0], M1 = mptr[1];
        float4 W0 = mptr[2], W1 = mptr[3], W2 = mptr[4];
        float4 W3 = mptr[5], W4 = mptr[6], W5 = mptr[7], W6 = mptr[8];

        int off[8];
        off[0] = __float_as_int(M0.x);
        off[1] = __float_as_int(M0.y);
        off[2] = __float_as_int(M0.z);
        off[3] = __float_as_int(M0.w);
        off[4] = __float_as_int(M1.x);
        off[5] = __float_as_int(M1.y);
        off[6] = __float_as_int(M1.z);
        off[7] = __float_as_int(M1.w);

#pragma unroll
        for (int g = 0; g < 3; ++g) {
            const int bg = bases[g];
            float a0[8], a1[8];
#pragma unroll
            for (int j = 0; j < 8; ++j) {
                const int ad = off[j] + bg;
                a0[j] = lds[ad];          // ds_read2_b32 {0,104}
                a1[j] = lds[ad + 104];
            }
            float yA = tree8(a0[0],a0[1],a0[2],a0[3],a0[4],a0[5],a0[6],a0[7],
                             W0,W1,W2,W3,W4,W5,W6);
            float yB = tree8(a1[0],a1[1],a1[2],a1[3],a1[4],a1[5],a1[6],a1[7],
                             W0,W1,W2,W3,W4,W5,W6);
            pbase[g * 32]      = yA;      // rows 0-1 of band
            pbase[g * 32 + 96] = yB;      // rows 2-3 of band (+2 rows = +96 px)
        }

        mptr  += META_F4;
        pbase += NPIX;
    }
}

extern "C" void kernel_launch(void* const* d_in, const int* in_sizes, int n_in,
                              void* d_out, int out_size, void* d_ws, size_t ws_size,
                              hipStream_t stream) {
    const float* x        = (const float*)d_in[0];
    const float* logits   = (const float*)d_in[1];
    const int*   leaf_idx = (const int*)d_in[2];
    float*       out      = (float*)d_out;
    float*       meta     = (float*)d_ws;    // 256*36 dwords = 36,864 B

    prep_kernel<<<15, 256, 0, stream>>>(logits, leaf_idx, meta);

    dim3 grid(12, 4, NB);
    ltc_kernel<<<grid, 512, 0, stream>>>(x, (const float4*)meta, out);
}